// Round 1
// baseline (1090.966 us; speedup 1.0000x reference)
//
#include <hip/hip_runtime.h>

#define D 64

// out[row][col] = sum_k feat[row][k] * W[col][k] + b[col]   (nn.Linear)
__global__ __launch_bounds__(256) void linear_kernel(
    const float* __restrict__ feat, const float* __restrict__ W,
    const float* __restrict__ b, float* __restrict__ out, int n_rows) {
    __shared__ float Wt[D * D];     // Wt[k*64+col] = W[col*64+k]
    __shared__ float fsh[4 * D];
    int t = threadIdx.x;            // 0..255
    for (int i = t; i < D * D; i += 256) {
        int col = i >> 6, k = i & 63;
        Wt[k * D + col] = W[i];     // i = col*64 + k
    }
    int r = t >> 6;                 // 0..3  (row within block)
    int lane = t & 63;              // output col
    int row = blockIdx.x * 4 + r;
    if (row < n_rows) fsh[r * D + lane] = feat[row * D + lane];
    __syncthreads();
    if (row >= n_rows) return;
    float acc = b[lane];
    #pragma unroll
    for (int k = 0; k < D; ++k)
        acc = fmaf(fsh[r * D + k], Wt[k * D + lane], acc);
    out[row * D + lane] = acc;
}

__global__ __launch_bounds__(256) void degree_kernel(
    const int* __restrict__ dst, float* __restrict__ deg, int n_edges) {
    int e = blockIdx.x * blockDim.x + threadIdx.x;
    if (e < n_edges) atomicAdd(&deg[dst[e]], 1.0f);
}

// one edge per 64 lanes: coalesced row gather + 64 consecutive atomicAdds
__global__ __launch_bounds__(256) void scatter_kernel(
    const float* __restrict__ Wh, const int* __restrict__ src,
    const int* __restrict__ dst, float* __restrict__ out, int n_edges) {
    int idx = blockIdx.x * blockDim.x + threadIdx.x;
    int e = idx >> 6;
    int lane = idx & 63;
    if (e >= n_edges) return;
    int s = src[e];
    int d = dst[e];
    atomicAdd(&out[d * D + lane], Wh[s * D + lane]);
}

// out[node][c] /= max(deg[node], 1)  over the concatenated (user,item) rows
__global__ __launch_bounds__(256) void finalize_kernel(
    float* __restrict__ out, const float* __restrict__ deg, int n_elems) {
    int idx = blockIdx.x * blockDim.x + threadIdx.x;
    if (idx >= n_elems) return;
    float dg = deg[idx >> 6];
    out[idx] = out[idx] / fmaxf(dg, 1.0f);
}

extern "C" void kernel_launch(void* const* d_in, const int* in_sizes, int n_in,
                              void* d_out, int out_size, void* d_ws, size_t ws_size,
                              hipStream_t stream) {
    const float* feat_user      = (const float*)d_in[0];
    const float* feat_item      = (const float*)d_in[1];
    const int*   src_clicks     = (const int*)d_in[2];   // user ids
    const int*   dst_clicks     = (const int*)d_in[3];   // item ids
    const int*   src_clicked_by = (const int*)d_in[4];   // item ids
    const int*   dst_clicked_by = (const int*)d_in[5];   // user ids
    const float* W_clicks       = (const float*)d_in[6];
    const float* b_clicks       = (const float*)d_in[7];
    const float* W_clicked_by   = (const float*)d_in[8];
    const float* b_clicked_by   = (const float*)d_in[9];

    const int n_user = in_sizes[0] / D;
    const int n_item = in_sizes[1] / D;
    const int n_edges = in_sizes[2];

    float* out = (float*)d_out;
    float* h_user = out;                     // [n_user, 64]
    float* h_item = out + (size_t)n_user * D; // [n_item, 64]

    // workspace layout
    float* Wh_user = (float*)d_ws;                           // [n_user, 64]
    float* Wh_item = Wh_user + (size_t)n_user * D;           // [n_item, 64]
    float* deg     = Wh_item + (size_t)n_item * D;           // [n_user + n_item]
    float* deg_user = deg;
    float* deg_item = deg + n_user;

    // zero-init output and degree scratch (poisoned to 0xAA before each call)
    hipMemsetAsync(d_out, 0, (size_t)out_size * sizeof(float), stream);
    hipMemsetAsync(deg, 0, (size_t)(n_user + n_item) * sizeof(float), stream);

    // per-relation Linear
    linear_kernel<<<(n_user + 3) / 4, 256, 0, stream>>>(
        feat_user, W_clicks, b_clicks, Wh_user, n_user);
    linear_kernel<<<(n_item + 3) / 4, 256, 0, stream>>>(
        feat_item, W_clicked_by, b_clicked_by, Wh_item, n_item);

    // degrees
    degree_kernel<<<(n_edges + 255) / 256, 256, 0, stream>>>(
        dst_clicked_by, deg_user, n_edges);
    degree_kernel<<<(n_edges + 255) / 256, 256, 0, stream>>>(
        dst_clicks, deg_item, n_edges);

    // scatter sums: h_user <- Wh_item over clicked_by edges; h_item <- Wh_user over clicks
    long long sc_threads = (long long)n_edges * D;
    int sc_blocks = (int)((sc_threads + 255) / 256);
    scatter_kernel<<<sc_blocks, 256, 0, stream>>>(
        Wh_item, src_clicked_by, dst_clicked_by, h_user, n_edges);
    scatter_kernel<<<sc_blocks, 256, 0, stream>>>(
        Wh_user, src_clicks, dst_clicks, h_item, n_edges);

    // mean = sum / max(deg,1) over the whole concatenated output
    int total = (n_user + n_item) * D;
    finalize_kernel<<<(total + 255) / 256, 256, 0, stream>>>(out, deg, total);
}

// Round 2
// 694.272 us; speedup vs baseline: 1.5714x; 1.5714x over previous
//
#include <hip/hip_runtime.h>

#define D 64
#define SCAN_BLOCK 256
#define SCAN_VPT 16
#define SCAN_TILE (SCAN_BLOCK * SCAN_VPT)   // 4096
#define LIN_ROWS 16

// out[row][col] = sum_k feat[row][k] * W[col][k] + b[col]   (nn.Linear)
// 16 rows per block; Wt padded stride 65 (conflict-free transpose write).
__global__ __launch_bounds__(256) void linear_kernel(
    const float* __restrict__ feat, const float* __restrict__ W,
    const float* __restrict__ b, float* __restrict__ out, int n_rows) {
    __shared__ float Wt[D * 65];          // Wt[k*65+col] = W[col*64+k]
    __shared__ float fsh[LIN_ROWS * D];
    int t = threadIdx.x;
    for (int i = t; i < D * D; i += 256) {
        int col = i >> 6, k = i & 63;
        Wt[k * 65 + col] = W[i];
    }
    int rbase = blockIdx.x * LIN_ROWS;
    for (int i = t; i < LIN_ROWS * D; i += 256) {
        int row = rbase + (i >> 6);
        fsh[i] = (row < n_rows) ? feat[(size_t)row * D + (i & 63)] : 0.f;
    }
    __syncthreads();
    int w = t >> 6, lane = t & 63;
    int r0 = w * 4;
    float bias = b[lane];
    float a0 = bias, a1 = bias, a2 = bias, a3 = bias;
    #pragma unroll
    for (int k = 0; k < D; ++k) {
        float wv = Wt[k * 65 + lane];
        a0 = fmaf(fsh[(r0 + 0) * D + k], wv, a0);
        a1 = fmaf(fsh[(r0 + 1) * D + k], wv, a1);
        a2 = fmaf(fsh[(r0 + 2) * D + k], wv, a2);
        a3 = fmaf(fsh[(r0 + 3) * D + k], wv, a3);
    }
    int row = rbase + r0;
    if (row + 0 < n_rows) out[(size_t)(row + 0) * D + lane] = a0;
    if (row + 1 < n_rows) out[(size_t)(row + 1) * D + lane] = a1;
    if (row + 2 < n_rows) out[(size_t)(row + 2) * D + lane] = a2;
    if (row + 3 < n_rows) out[(size_t)(row + 3) * D + lane] = a3;
}

__global__ __launch_bounds__(256) void count_kernel(
    const int* __restrict__ dst, int* __restrict__ deg, int n_edges) {
    int e = blockIdx.x * blockDim.x + threadIdx.x;
    if (e < n_edges) atomicAdd(&deg[dst[e]], 1);
}

// ---- 3-phase exclusive scan over n (grid.y selects relation) ----
__global__ __launch_bounds__(SCAN_BLOCK) void scan_block_sums(
    const int* __restrict__ deg0, const int* __restrict__ deg1,
    int* __restrict__ bs0, int* __restrict__ bs1, int n) {
    const int* deg = blockIdx.y ? deg1 : deg0;
    int* bs = blockIdx.y ? bs1 : bs0;
    int t = threadIdx.x;
    int base = blockIdx.x * SCAN_TILE + t * SCAN_VPT;
    int s = 0;
    #pragma unroll
    for (int i = 0; i < SCAN_VPT; ++i)
        if (base + i < n) s += deg[base + i];
    __shared__ int red[SCAN_BLOCK];
    red[t] = s;
    __syncthreads();
    for (int off = SCAN_BLOCK / 2; off > 0; off >>= 1) {
        if (t < off) red[t] += red[t + off];
        __syncthreads();
    }
    if (t == 0) bs[blockIdx.x] = red[0];
}

__global__ void scan_partials(int* __restrict__ bs0, int* __restrict__ bs1, int nb) {
    int* bs = blockIdx.y ? bs1 : bs0;
    if (threadIdx.x == 0) {
        int running = 0;
        for (int i = 0; i < nb; ++i) {
            int v = bs[i];
            bs[i] = running;
            running += v;
        }
    }
}

__global__ __launch_bounds__(SCAN_BLOCK) void scan_final(
    const int* __restrict__ deg0, const int* __restrict__ deg1,
    const int* __restrict__ bs0, const int* __restrict__ bs1,
    int* __restrict__ off0, int* __restrict__ off1,
    int* __restrict__ cur0, int* __restrict__ cur1, int n) {
    const int* deg = blockIdx.y ? deg1 : deg0;
    const int* bs  = blockIdx.y ? bs1 : bs0;
    int* off = blockIdx.y ? off1 : off0;
    int* cur = blockIdx.y ? cur1 : cur0;
    int t = threadIdx.x;
    int base = blockIdx.x * SCAN_TILE + t * SCAN_VPT;
    int v[SCAN_VPT];
    int tsum = 0;
    #pragma unroll
    for (int i = 0; i < SCAN_VPT; ++i) {
        v[i] = (base + i < n) ? deg[base + i] : 0;
        tsum += v[i];
    }
    __shared__ int ts[SCAN_BLOCK];
    ts[t] = tsum;
    __syncthreads();
    // Hillis-Steele inclusive scan
    for (int o = 1; o < SCAN_BLOCK; o <<= 1) {
        int x = (t >= o) ? ts[t - o] : 0;
        __syncthreads();
        ts[t] += x;
        __syncthreads();
    }
    int run = ts[t] - tsum + bs[blockIdx.x];   // exclusive prefix for this thread
    #pragma unroll
    for (int i = 0; i < SCAN_VPT; ++i) {
        if (base + i < n) { off[base + i] = run; cur[base + i] = run; }
        run += v[i];
    }
}

__global__ __launch_bounds__(256) void fill_kernel(
    const int* __restrict__ src, const int* __restrict__ dst,
    int* __restrict__ cur, int* __restrict__ csr_src, int n_edges) {
    int e = blockIdx.x * blockDim.x + threadIdx.x;
    if (e >= n_edges) return;
    int d = dst[e];
    int p = atomicAdd(&cur[d], 1);
    csr_src[p] = src[e];
}

// one wave per dst node: gather rows of Wh by csr src ids, mean, write once
__global__ __launch_bounds__(256) void gather_kernel(
    const float* __restrict__ Wh, const int* __restrict__ csr_src,
    const int* __restrict__ off, const int* __restrict__ deg,
    float* __restrict__ out, int n_nodes) {
    int t = threadIdx.x;
    int node = blockIdx.x * 4 + (t >> 6);
    int lane = t & 63;
    if (node >= n_nodes) return;
    int start = off[node];
    int dg = deg[node];
    float acc = 0.f;
    for (int base = 0; base < dg; base += 64) {
        int m = min(64, dg - base);
        int sidx = (lane < m) ? csr_src[start + base + lane] : 0;
        for (int j = 0; j < m; ++j) {
            int s = __shfl(sidx, j, 64);
            acc += Wh[(size_t)s * D + lane];
        }
    }
    out[(size_t)node * D + lane] = acc / fmaxf((float)dg, 1.0f);
}

extern "C" void kernel_launch(void* const* d_in, const int* in_sizes, int n_in,
                              void* d_out, int out_size, void* d_ws, size_t ws_size,
                              hipStream_t stream) {
    const float* feat_user      = (const float*)d_in[0];
    const float* feat_item      = (const float*)d_in[1];
    const int*   src_clicks     = (const int*)d_in[2];   // user ids
    const int*   dst_clicks     = (const int*)d_in[3];   // item ids
    const int*   src_clicked_by = (const int*)d_in[4];   // item ids
    const int*   dst_clicked_by = (const int*)d_in[5];   // user ids
    const float* W_clicks       = (const float*)d_in[6];
    const float* b_clicks       = (const float*)d_in[7];
    const float* W_clicked_by   = (const float*)d_in[8];
    const float* b_clicked_by   = (const float*)d_in[9];

    const int n_user  = in_sizes[0] / D;
    const int n_item  = in_sizes[1] / D;
    const int n_edges = in_sizes[2];

    float* out = (float*)d_out;
    float* h_user = out;                       // [n_user, 64]
    float* h_item = out + (size_t)n_user * D;  // [n_item, 64]

    // workspace layout
    float* Wh_user = (float*)d_ws;                     // [n_user*64]
    float* Wh_item = Wh_user + (size_t)n_user * D;     // [n_item*64]
    int* ip        = (int*)(Wh_item + (size_t)n_item * D);
    int* deg_user  = ip;             ip += n_user;
    int* deg_item  = ip;             ip += n_item;
    int* off_user  = ip;             ip += n_user;
    int* off_item  = ip;             ip += n_item;
    int* cur_user  = ip;             ip += n_user;
    int* cur_item  = ip;             ip += n_item;
    int* bs_user   = ip;             ip += 64;
    int* bs_item   = ip;             ip += 64;
    int* csr_user  = ip;             ip += n_edges;    // srcs (item ids) grouped by user dst
    int* csr_item  = ip;                               // srcs (user ids) grouped by item dst

    // zero only the degree counters
    hipMemsetAsync(deg_user, 0, (size_t)(n_user + n_item) * sizeof(int), stream);

    // per-relation Linear
    linear_kernel<<<(n_user + LIN_ROWS - 1) / LIN_ROWS, 256, 0, stream>>>(
        feat_user, W_clicks, b_clicks, Wh_user, n_user);
    linear_kernel<<<(n_item + LIN_ROWS - 1) / LIN_ROWS, 256, 0, stream>>>(
        feat_item, W_clicked_by, b_clicked_by, Wh_item, n_item);

    // degree histograms
    count_kernel<<<(n_edges + 255) / 256, 256, 0, stream>>>(dst_clicked_by, deg_user, n_edges);
    count_kernel<<<(n_edges + 255) / 256, 256, 0, stream>>>(dst_clicks, deg_item, n_edges);

    // exclusive scans (both relations via grid.y; n_user == n_item == 100000)
    int nb_u = (n_user + SCAN_TILE - 1) / SCAN_TILE;
    dim3 gA(nb_u, 2);
    scan_block_sums<<<gA, SCAN_BLOCK, 0, stream>>>(deg_user, deg_item, bs_user, bs_item, n_user);
    scan_partials<<<dim3(1, 2), 64, 0, stream>>>(bs_user, bs_item, nb_u);
    scan_final<<<gA, SCAN_BLOCK, 0, stream>>>(deg_user, deg_item, bs_user, bs_item,
                                              off_user, off_item, cur_user, cur_item, n_user);

    // CSR fill
    fill_kernel<<<(n_edges + 255) / 256, 256, 0, stream>>>(
        src_clicked_by, dst_clicked_by, cur_user, csr_user, n_edges);
    fill_kernel<<<(n_edges + 255) / 256, 256, 0, stream>>>(
        src_clicks, dst_clicks, cur_item, csr_item, n_edges);

    // gather + mean (fused finalize); writes every output row -> no d_out memset
    gather_kernel<<<(n_user + 3) / 4, 256, 0, stream>>>(
        Wh_item, csr_user, off_user, deg_user, h_user, n_user);
    gather_kernel<<<(n_item + 3) / 4, 256, 0, stream>>>(
        Wh_user, csr_item, off_item, deg_item, h_item, n_item);
}

// Round 3
// 592.892 us; speedup vs baseline: 1.8401x; 1.1710x over previous
//
#include <hip/hip_runtime.h>

#define D 64
#define SCAN_BLOCK 256
#define SCAN_VPT 16
#define SCAN_TILE (SCAN_BLOCK * SCAN_VPT)   // 4096
#define ROWS_PER_WAVE 8
#define ROWS_PER_BLOCK (4 * ROWS_PER_WAVE)  // 32

// Fused two-relation Linear. lane = output col; W row `lane` (i.e. column of
// W^T) lives in 64 VGPRs; feat rows read via wave-uniform float4 loads
// (scalar path) -> no LDS, no barriers. 8 rows per wave.
__global__ __launch_bounds__(256) void linear2_kernel(
    const float* __restrict__ feat_u, const float* __restrict__ feat_i,
    const float* __restrict__ W_c, const float* __restrict__ b_c,
    const float* __restrict__ W_cb, const float* __restrict__ b_cb,
    float* __restrict__ Wh_u, float* __restrict__ Wh_i,
    int n_user, int n_item, int nb_u) {
    int blk = blockIdx.x;
    const float* feat; const float* W; const float* b; float* out; int n; int tile;
    if (blk < nb_u) { feat = feat_u; W = W_c;  b = b_c;  out = Wh_u; n = n_user; tile = blk; }
    else            { feat = feat_i; W = W_cb; b = b_cb; out = Wh_i; n = n_item; tile = blk - nb_u; }

    int lane = threadIdx.x & 63;
    int wid = __builtin_amdgcn_readfirstlane(threadIdx.x >> 6);   // uniform wave id

    float4 w[16];                         // W[lane][0..63] in registers
    #pragma unroll
    for (int k4 = 0; k4 < 16; ++k4)
        w[k4] = *(const float4*)(W + lane * D + k4 * 4);
    float bias = b[lane];

    int r0 = tile * ROWS_PER_BLOCK + wid * ROWS_PER_WAVE;         // uniform
    if (r0 >= n) return;

    float acc[ROWS_PER_WAVE];
    #pragma unroll
    for (int r = 0; r < ROWS_PER_WAVE; ++r) acc[r] = bias;

    #pragma unroll
    for (int k4 = 0; k4 < 16; ++k4) {
        #pragma unroll
        for (int r = 0; r < ROWS_PER_WAVE; ++r) {
            int row = r0 + r; if (row > n - 1) row = n - 1;        // uniform, CSE'd
            float4 f = *(const float4*)(feat + (size_t)row * D + k4 * 4);
            acc[r] = fmaf(f.x, w[k4].x, acc[r]);
            acc[r] = fmaf(f.y, w[k4].y, acc[r]);
            acc[r] = fmaf(f.z, w[k4].z, acc[r]);
            acc[r] = fmaf(f.w, w[k4].w, acc[r]);
        }
    }
    #pragma unroll
    for (int r = 0; r < ROWS_PER_WAVE; ++r) {
        int row = r0 + r;
        if (row < n) out[(size_t)row * D + lane] = acc[r];
    }
}

// fused degree histograms (blockIdx.y selects relation)
__global__ __launch_bounds__(256) void count2_kernel(
    const int* __restrict__ dstA, const int* __restrict__ dstB,
    int* __restrict__ degA, int* __restrict__ degB, int n_edges) {
    const int* dst = blockIdx.y ? dstB : dstA;
    int* deg = blockIdx.y ? degB : degA;
    int e = blockIdx.x * blockDim.x + threadIdx.x;
    if (e < n_edges) atomicAdd(&deg[dst[e]], 1);
}

// ---- 3-phase exclusive scan over n (grid.y selects relation) ----
__global__ __launch_bounds__(SCAN_BLOCK) void scan_block_sums(
    const int* __restrict__ deg0, const int* __restrict__ deg1,
    int* __restrict__ bs0, int* __restrict__ bs1, int n) {
    const int* deg = blockIdx.y ? deg1 : deg0;
    int* bs = blockIdx.y ? bs1 : bs0;
    int t = threadIdx.x;
    int base = blockIdx.x * SCAN_TILE + t * SCAN_VPT;
    int s = 0;
    #pragma unroll
    for (int i = 0; i < SCAN_VPT; ++i)
        if (base + i < n) s += deg[base + i];
    __shared__ int red[SCAN_BLOCK];
    red[t] = s;
    __syncthreads();
    for (int off = SCAN_BLOCK / 2; off > 0; off >>= 1) {
        if (t < off) red[t] += red[t + off];
        __syncthreads();
    }
    if (t == 0) bs[blockIdx.x] = red[0];
}

__global__ void scan_partials(int* __restrict__ bs0, int* __restrict__ bs1, int nb) {
    int* bs = blockIdx.y ? bs1 : bs0;
    if (threadIdx.x == 0) {
        int running = 0;
        for (int i = 0; i < nb; ++i) {
            int v = bs[i];
            bs[i] = running;
            running += v;
        }
    }
}

__global__ __launch_bounds__(SCAN_BLOCK) void scan_final(
    const int* __restrict__ deg0, const int* __restrict__ deg1,
    const int* __restrict__ bs0, const int* __restrict__ bs1,
    int* __restrict__ off0, int* __restrict__ off1,
    int* __restrict__ cur0, int* __restrict__ cur1, int n) {
    const int* deg = blockIdx.y ? deg1 : deg0;
    const int* bs  = blockIdx.y ? bs1 : bs0;
    int* off = blockIdx.y ? off1 : off0;
    int* cur = blockIdx.y ? cur1 : cur0;
    int t = threadIdx.x;
    int base = blockIdx.x * SCAN_TILE + t * SCAN_VPT;
    int v[SCAN_VPT];
    int tsum = 0;
    #pragma unroll
    for (int i = 0; i < SCAN_VPT; ++i) {
        v[i] = (base + i < n) ? deg[base + i] : 0;
        tsum += v[i];
    }
    __shared__ int ts[SCAN_BLOCK];
    ts[t] = tsum;
    __syncthreads();
    for (int o = 1; o < SCAN_BLOCK; o <<= 1) {
        int x = (t >= o) ? ts[t - o] : 0;
        __syncthreads();
        ts[t] += x;
        __syncthreads();
    }
    int run = ts[t] - tsum + bs[blockIdx.x];
    #pragma unroll
    for (int i = 0; i < SCAN_VPT; ++i) {
        if (base + i < n) { off[base + i] = run; cur[base + i] = run; }
        run += v[i];
    }
}

// fused CSR fill (blockIdx.y selects relation)
__global__ __launch_bounds__(256) void fill2_kernel(
    const int* __restrict__ srcA, const int* __restrict__ dstA,
    const int* __restrict__ srcB, const int* __restrict__ dstB,
    int* __restrict__ curA, int* __restrict__ curB,
    int* __restrict__ csrA, int* __restrict__ csrB, int n_edges) {
    const int* src = blockIdx.y ? srcB : srcA;
    const int* dst = blockIdx.y ? dstB : dstA;
    int* cur = blockIdx.y ? curB : curA;
    int* csr = blockIdx.y ? csrB : csrA;
    int e = blockIdx.x * blockDim.x + threadIdx.x;
    if (e >= n_edges) return;
    int d = dst[e];
    int p = atomicAdd(&cur[d], 1);
    csr[p] = src[e];
}

// fused gather+mean: one wave per dst node (blockIdx.y selects relation)
__global__ __launch_bounds__(256) void gather2_kernel(
    const float* __restrict__ Wh_u, const float* __restrict__ Wh_i,
    const int* __restrict__ csr_u, const int* __restrict__ csr_i,
    const int* __restrict__ off_u, const int* __restrict__ off_i,
    const int* __restrict__ deg_u, const int* __restrict__ deg_i,
    float* __restrict__ h_user, float* __restrict__ h_item,
    int n_user, int n_item) {
    const float* Wh; const int* csr; const int* off; const int* deg;
    float* out; int n;
    if (blockIdx.y == 0) { Wh = Wh_i; csr = csr_u; off = off_u; deg = deg_u; out = h_user; n = n_user; }
    else                 { Wh = Wh_u; csr = csr_i; off = off_i; deg = deg_i; out = h_item; n = n_item; }
    int t = threadIdx.x;
    int node = blockIdx.x * 4 + (t >> 6);
    int lane = t & 63;
    if (node >= n) return;
    int start = off[node];
    int dg = deg[node];
    float acc = 0.f;
    for (int base = 0; base < dg; base += 64) {
        int m = min(64, dg - base);
        int sidx = (lane < m) ? csr[start + base + lane] : 0;
        for (int j = 0; j < m; ++j) {
            int s = __shfl(sidx, j, 64);
            acc += Wh[(size_t)s * D + lane];
        }
    }
    out[(size_t)node * D + lane] = acc / fmaxf((float)dg, 1.0f);
}

extern "C" void kernel_launch(void* const* d_in, const int* in_sizes, int n_in,
                              void* d_out, int out_size, void* d_ws, size_t ws_size,
                              hipStream_t stream) {
    const float* feat_user      = (const float*)d_in[0];
    const float* feat_item      = (const float*)d_in[1];
    const int*   src_clicks     = (const int*)d_in[2];   // user ids
    const int*   dst_clicks     = (const int*)d_in[3];   // item ids
    const int*   src_clicked_by = (const int*)d_in[4];   // item ids
    const int*   dst_clicked_by = (const int*)d_in[5];   // user ids
    const float* W_clicks       = (const float*)d_in[6];
    const float* b_clicks       = (const float*)d_in[7];
    const float* W_clicked_by   = (const float*)d_in[8];
    const float* b_clicked_by   = (const float*)d_in[9];

    const int n_user  = in_sizes[0] / D;
    const int n_item  = in_sizes[1] / D;
    const int n_edges = in_sizes[2];

    float* out = (float*)d_out;
    float* h_user = out;
    float* h_item = out + (size_t)n_user * D;

    float* Wh_user = (float*)d_ws;
    float* Wh_item = Wh_user + (size_t)n_user * D;
    int* ip        = (int*)(Wh_item + (size_t)n_item * D);
    int* deg_user  = ip;             ip += n_user;
    int* deg_item  = ip;             ip += n_item;
    int* off_user  = ip;             ip += n_user;
    int* off_item  = ip;             ip += n_item;
    int* cur_user  = ip;             ip += n_user;
    int* cur_item  = ip;             ip += n_item;
    int* bs_user   = ip;             ip += 64;
    int* bs_item   = ip;             ip += 64;
    int* csr_user  = ip;             ip += n_edges;
    int* csr_item  = ip;

    hipMemsetAsync(deg_user, 0, (size_t)(n_user + n_item) * sizeof(int), stream);

    // fused linears
    int nb_u = (n_user + ROWS_PER_BLOCK - 1) / ROWS_PER_BLOCK;
    int nb_i = (n_item + ROWS_PER_BLOCK - 1) / ROWS_PER_BLOCK;
    linear2_kernel<<<nb_u + nb_i, 256, 0, stream>>>(
        feat_user, feat_item, W_clicks, b_clicks, W_clicked_by, b_clicked_by,
        Wh_user, Wh_item, n_user, n_item, nb_u);

    // fused degree histograms (A: user dsts, B: item dsts)
    dim3 gC((n_edges + 255) / 256, 2);
    count2_kernel<<<gC, 256, 0, stream>>>(dst_clicked_by, dst_clicks,
                                          deg_user, deg_item, n_edges);

    // exclusive scans (n_user == n_item)
    int nb_s = (n_user + SCAN_TILE - 1) / SCAN_TILE;
    dim3 gA(nb_s, 2);
    scan_block_sums<<<gA, SCAN_BLOCK, 0, stream>>>(deg_user, deg_item, bs_user, bs_item, n_user);
    scan_partials<<<dim3(1, 2), 64, 0, stream>>>(bs_user, bs_item, nb_s);
    scan_final<<<gA, SCAN_BLOCK, 0, stream>>>(deg_user, deg_item, bs_user, bs_item,
                                              off_user, off_item, cur_user, cur_item, n_user);

    // fused CSR fill
    fill2_kernel<<<gC, 256, 0, stream>>>(src_clicked_by, dst_clicked_by,
                                         src_clicks, dst_clicks,
                                         cur_user, cur_item, csr_user, csr_item, n_edges);

    // fused gather + mean
    dim3 gG((max(n_user, n_item) + 3) / 4, 2);
    gather2_kernel<<<gG, 256, 0, stream>>>(
        Wh_user, Wh_item, csr_user, csr_item, off_user, off_item,
        deg_user, deg_item, h_user, h_item, n_user, n_item);
}

// Round 4
// 392.886 us; speedup vs baseline: 2.7768x; 1.5091x over previous
//
#include <hip/hip_runtime.h>

#define D 64
#define NB 512            // dst buckets (bucket = dst >> 8); covers n < 131072
#define CHUNK 4096        // edges per bucket_fill/count block
#define EPT (CHUNK / 256) // 16 edges per thread
#define TILE 64           // rows per linear block

// ---------------- Linear: out = feat @ W^T + b, 64x64x64 tile GEMM ----------------
__global__ __launch_bounds__(256) void linear_gemm(
    const float* __restrict__ feat_u, const float* __restrict__ feat_i,
    const float* __restrict__ W_c, const float* __restrict__ b_c,
    const float* __restrict__ W_cb, const float* __restrict__ b_cb,
    float* __restrict__ Wh_u, float* __restrict__ Wh_i,
    int n_user, int n_item) {
    const float* feat; const float* W; const float* bia; float* out; int n;
    if (blockIdx.y == 0) { feat = feat_u; W = W_c;  bia = b_c;  out = Wh_u; n = n_user; }
    else                 { feat = feat_i; W = W_cb; bia = b_cb; out = Wh_i; n = n_item; }
    int row0 = blockIdx.x * TILE;
    if (row0 >= n) return;
    __shared__ float FT[D * 68];   // FT[k*68 + r] = feat[row0+r][k]
    __shared__ float WT[D * 68];   // WT[k*68 + c] = W[c][k]
    int t = threadIdx.x;
    int lr = t >> 4;               // 0..15
    int k4 = (t & 15) * 4;
    #pragma unroll
    for (int it = 0; it < 4; ++it) {
        int r = lr + it * 16;      // 0..63
        int grow = row0 + r; if (grow > n - 1) grow = n - 1;
        float4 f = *(const float4*)(feat + (size_t)grow * D + k4);
        FT[(k4 + 0) * 68 + r] = f.x;
        FT[(k4 + 1) * 68 + r] = f.y;
        FT[(k4 + 2) * 68 + r] = f.z;
        FT[(k4 + 3) * 68 + r] = f.w;
        float4 w = *(const float4*)(W + r * D + k4);   // W[col=r][k4..k4+3]
        WT[(k4 + 0) * 68 + r] = w.x;
        WT[(k4 + 1) * 68 + r] = w.y;
        WT[(k4 + 2) * 68 + r] = w.z;
        WT[(k4 + 3) * 68 + r] = w.w;
    }
    __syncthreads();
    int r0 = (t & 15) * 4;
    int c0 = (t >> 4) * 4;
    float4 bv = *(const float4*)(bia + c0);
    float acc[4][4];
    #pragma unroll
    for (int ri = 0; ri < 4; ++ri) {
        acc[ri][0] = bv.x; acc[ri][1] = bv.y; acc[ri][2] = bv.z; acc[ri][3] = bv.w;
    }
    #pragma unroll
    for (int k = 0; k < D; ++k) {
        float4 f = *(const float4*)(FT + k * 68 + r0);
        float4 w = *(const float4*)(WT + k * 68 + c0);
        acc[0][0] = fmaf(f.x, w.x, acc[0][0]); acc[0][1] = fmaf(f.x, w.y, acc[0][1]);
        acc[0][2] = fmaf(f.x, w.z, acc[0][2]); acc[0][3] = fmaf(f.x, w.w, acc[0][3]);
        acc[1][0] = fmaf(f.y, w.x, acc[1][0]); acc[1][1] = fmaf(f.y, w.y, acc[1][1]);
        acc[1][2] = fmaf(f.y, w.z, acc[1][2]); acc[1][3] = fmaf(f.y, w.w, acc[1][3]);
        acc[2][0] = fmaf(f.z, w.x, acc[2][0]); acc[2][1] = fmaf(f.z, w.y, acc[2][1]);
        acc[2][2] = fmaf(f.z, w.z, acc[2][2]); acc[2][3] = fmaf(f.z, w.w, acc[2][3]);
        acc[3][0] = fmaf(f.w, w.x, acc[3][0]); acc[3][1] = fmaf(f.w, w.y, acc[3][1]);
        acc[3][2] = fmaf(f.w, w.z, acc[3][2]); acc[3][3] = fmaf(f.w, w.w, acc[3][3]);
    }
    #pragma unroll
    for (int ri = 0; ri < 4; ++ri) {
        int row = row0 + r0 + ri;
        if (row < n) {
            float4 o; o.x = acc[ri][0]; o.y = acc[ri][1]; o.z = acc[ri][2]; o.w = acc[ri][3];
            *(float4*)(out + (size_t)row * D + c0) = o;
        }
    }
}

// ---------------- Pass A: coarse bucket histogram ----------------
__global__ __launch_bounds__(256) void bucket_count(
    const int* __restrict__ dstA, const int* __restrict__ dstB,
    int* __restrict__ bcnt, int n_edges) {
    const int* dst = blockIdx.y ? dstB : dstA;
    int* bc = bcnt + blockIdx.y * NB;
    __shared__ int hist[NB];
    int t = threadIdx.x;
    for (int i = t; i < NB; i += 256) hist[i] = 0;
    __syncthreads();
    int base = blockIdx.x * CHUNK;
    #pragma unroll
    for (int j = 0; j < EPT; ++j) {
        int e = base + j * 256 + t;
        if (e < n_edges) atomicAdd(&hist[((unsigned)dst[e]) >> 8], 1);
    }
    __syncthreads();
    for (int i = t; i < NB; i += 256) if (hist[i]) atomicAdd(&bc[i], hist[i]);
}

// ---------------- tiny scan over NB bucket counts ----------------
__global__ __launch_bounds__(256) void bucket_scan(
    const int* __restrict__ bcnt, int* __restrict__ bbase, int* __restrict__ bcur) {
    int rel = blockIdx.y;
    const int* bc = bcnt + rel * NB;
    int* bb = bbase + rel * NB;
    int* bu = bcur + rel * NB;
    __shared__ int ps[256];
    int t = threadIdx.x;
    int a0 = bc[2 * t], a1 = bc[2 * t + 1];
    ps[t] = a0 + a1;
    __syncthreads();
    for (int o = 1; o < 256; o <<= 1) {
        int x = (t >= o) ? ps[t - o] : 0;
        __syncthreads();
        ps[t] += x;
        __syncthreads();
    }
    int ex = ps[t] - (a0 + a1);
    bb[2 * t] = ex;          bu[2 * t] = ex;
    bb[2 * t + 1] = ex + a0; bu[2 * t + 1] = ex + a0;
}

// ---------------- Pass B: bucket-partition edges (LDS reorder, run writes) ----------------
__global__ __launch_bounds__(256) void bucket_fill(
    const int* __restrict__ srcA, const int* __restrict__ dstA,
    const int* __restrict__ srcB, const int* __restrict__ dstB,
    int* __restrict__ bcur,
    unsigned int* __restrict__ ebufA, unsigned int* __restrict__ ebufB,
    int n_edges) {
    int rel = blockIdx.y;
    const int* src = rel ? srcB : srcA;
    const int* dst = rel ? dstB : dstA;
    int* bu = bcur + rel * NB;
    unsigned int* ebuf = rel ? ebufB : ebufA;
    __shared__ int hist[NB], lofs[NB], lcur[NB], runb[NB];
    __shared__ unsigned int stage[CHUNK];
    __shared__ unsigned short sbkt[CHUNK];
    __shared__ int ps[256];
    int t = threadIdx.x;
    for (int i = t; i < NB; i += 256) hist[i] = 0;
    __syncthreads();
    int base = blockIdx.x * CHUNK;
    int m = n_edges - base; if (m > CHUNK) m = CHUNK;
    unsigned int packed[EPT];
    int bk[EPT];
    #pragma unroll
    for (int j = 0; j < EPT; ++j) {
        int e = base + j * 256 + t;
        if (e < n_edges) {
            int d = dst[e];
            int s = src[e];
            bk[j] = ((unsigned)d) >> 8;
            packed[j] = (unsigned int)s | (((unsigned int)d & 255u) << 24);
            atomicAdd(&hist[bk[j]], 1);
        } else bk[j] = -1;
    }
    __syncthreads();
    // exclusive scan of hist[0..NB) via 256-thread pair scan
    int a0 = hist[2 * t], a1 = hist[2 * t + 1];
    ps[t] = a0 + a1;
    __syncthreads();
    for (int o = 1; o < 256; o <<= 1) {
        int x = (t >= o) ? ps[t - o] : 0;
        __syncthreads();
        ps[t] += x;
        __syncthreads();
    }
    int ex = ps[t] - (a0 + a1);
    lofs[2 * t] = ex;          lcur[2 * t] = ex;
    lofs[2 * t + 1] = ex + a0; lcur[2 * t + 1] = ex + a0;
    __syncthreads();
    // reserve global runs (one atomic per non-empty bucket per block)
    for (int b = t; b < NB; b += 256) {
        int c = hist[b];
        runb[b] = c ? atomicAdd(&bu[b], c) : 0;
    }
    // reorder into LDS stage
    #pragma unroll
    for (int j = 0; j < EPT; ++j) {
        if (bk[j] >= 0) {
            int p = atomicAdd(&lcur[bk[j]], 1);
            stage[p] = packed[j];
            sbkt[p] = (unsigned short)bk[j];
        }
    }
    __syncthreads();
    // sequential run copy-out: consecutive i in a bucket -> consecutive global slots
    for (int i = t; i < m; i += 256) {
        int b = sbkt[i];
        ebuf[runb[b] + (i - lofs[b])] = stage[i];
    }
}

// ---------------- Pass C: per-bucket node degrees, offsets, csr ----------------
__global__ __launch_bounds__(256) void bucket_csr(
    const unsigned int* __restrict__ ebufA, const unsigned int* __restrict__ ebufB,
    const int* __restrict__ bcnt, const int* __restrict__ bbase,
    int* __restrict__ degA, int* __restrict__ degB,
    int* __restrict__ offA, int* __restrict__ offB,
    int* __restrict__ csrA, int* __restrict__ csrB, int n) {
    int rel = blockIdx.y;
    const unsigned int* ebuf = rel ? ebufB : ebufA;
    int* deg = rel ? degB : degA;
    int* off = rel ? offB : offA;
    int* csr = rel ? csrB : csrA;
    int b = blockIdx.x;
    int cnt = bcnt[rel * NB + b];
    int eb  = bbase[rel * NB + b];
    __shared__ int ndeg[256], nofs[256], ncur[256];
    int t = threadIdx.x;
    ndeg[t] = 0;
    __syncthreads();
    for (int i = t; i < cnt; i += 256)
        atomicAdd(&ndeg[ebuf[eb + i] >> 24], 1);
    __syncthreads();
    int own = ndeg[t];
    nofs[t] = own;
    __syncthreads();
    for (int o = 1; o < 256; o <<= 1) {
        int x = (t >= o) ? nofs[t - o] : 0;
        __syncthreads();
        nofs[t] += x;
        __syncthreads();
    }
    int ex = nofs[t] - own;
    int node = b * 256 + t;
    if (node < n) { deg[node] = own; off[node] = eb + ex; }
    ncur[t] = ex;
    __syncthreads();
    for (int i = t; i < cnt; i += 256) {
        unsigned int v = ebuf[eb + i];
        int ln = v >> 24;
        int p = atomicAdd(&ncur[ln], 1);
        csr[eb + p] = (int)(v & 0xFFFFFFu);
    }
}

// ---------------- gather + mean: one wave per dst node ----------------
__global__ __launch_bounds__(256) void gather2_kernel(
    const float* __restrict__ Wh_u, const float* __restrict__ Wh_i,
    const int* __restrict__ csr_u, const int* __restrict__ csr_i,
    const int* __restrict__ off_u, const int* __restrict__ off_i,
    const int* __restrict__ deg_u, const int* __restrict__ deg_i,
    float* __restrict__ h_user, float* __restrict__ h_item,
    int n_user, int n_item) {
    const float* Wh; const int* csr; const int* off; const int* deg;
    float* out; int n;
    if (blockIdx.y == 0) { Wh = Wh_i; csr = csr_u; off = off_u; deg = deg_u; out = h_user; n = n_user; }
    else                 { Wh = Wh_u; csr = csr_i; off = off_i; deg = deg_i; out = h_item; n = n_item; }
    int t = threadIdx.x;
    int node = blockIdx.x * 4 + (t >> 6);
    int lane = t & 63;
    if (node >= n) return;
    int start = off[node];
    int dg = deg[node];
    float acc = 0.f;
    for (int base = 0; base < dg; base += 64) {
        int m = min(64, dg - base);
        int sidx = (lane < m) ? csr[start + base + lane] : 0;
        for (int j = 0; j < m; ++j) {
            int s = __shfl(sidx, j, 64);
            acc += Wh[(size_t)s * D + lane];
        }
    }
    out[(size_t)node * D + lane] = acc / fmaxf((float)dg, 1.0f);
}

extern "C" void kernel_launch(void* const* d_in, const int* in_sizes, int n_in,
                              void* d_out, int out_size, void* d_ws, size_t ws_size,
                              hipStream_t stream) {
    const float* feat_user      = (const float*)d_in[0];
    const float* feat_item      = (const float*)d_in[1];
    const int*   src_clicks     = (const int*)d_in[2];   // user ids
    const int*   dst_clicks     = (const int*)d_in[3];   // item ids
    const int*   src_clicked_by = (const int*)d_in[4];   // item ids
    const int*   dst_clicked_by = (const int*)d_in[5];   // user ids
    const float* W_clicks       = (const float*)d_in[6];
    const float* b_clicks       = (const float*)d_in[7];
    const float* W_clicked_by   = (const float*)d_in[8];
    const float* b_clicked_by   = (const float*)d_in[9];

    const int n_user  = in_sizes[0] / D;
    const int n_item  = in_sizes[1] / D;
    const int n_edges = in_sizes[2];

    float* out = (float*)d_out;
    float* h_user = out;
    float* h_item = out + (size_t)n_user * D;

    float* Wh_user = (float*)d_ws;
    float* Wh_item = Wh_user + (size_t)n_user * D;
    int* ip        = (int*)(Wh_item + (size_t)n_item * D);
    int* deg_user  = ip;                      ip += n_user;
    int* deg_item  = ip;                      ip += n_item;
    int* off_user  = ip;                      ip += n_user;
    int* off_item  = ip;                      ip += n_item;
    int* csr_user  = ip;                      ip += n_edges;
    int* csr_item  = ip;                      ip += n_edges;
    unsigned int* ebuf_user = (unsigned int*)ip;  ip += n_edges;
    unsigned int* ebuf_item = (unsigned int*)ip;  ip += n_edges;
    int* bcnt  = ip;                          ip += 2 * NB;
    int* bbase = ip;                          ip += 2 * NB;
    int* bcur  = ip;

    // zero only the bucket counters (4 KB)
    hipMemsetAsync(bcnt, 0, 2 * NB * sizeof(int), stream);

    // linears (tiled GEMM, both relations)
    int ntile = (max(n_user, n_item) + TILE - 1) / TILE;
    linear_gemm<<<dim3(ntile, 2), 256, 0, stream>>>(
        feat_user, feat_item, W_clicks, b_clicks, W_clicked_by, b_clicked_by,
        Wh_user, Wh_item, n_user, n_item);

    // two-level bucket sort of edges by dst
    int eb = (n_edges + CHUNK - 1) / CHUNK;
    bucket_count<<<dim3(eb, 2), 256, 0, stream>>>(dst_clicked_by, dst_clicks, bcnt, n_edges);
    bucket_scan<<<dim3(1, 2), 256, 0, stream>>>(bcnt, bbase, bcur);
    bucket_fill<<<dim3(eb, 2), 256, 0, stream>>>(
        src_clicked_by, dst_clicked_by, src_clicks, dst_clicks,
        bcur, ebuf_user, ebuf_item, n_edges);
    int nbk = (max(n_user, n_item) + 255) >> 8;
    bucket_csr<<<dim3(nbk, 2), 256, 0, stream>>>(
        ebuf_user, ebuf_item, bcnt, bbase,
        deg_user, deg_item, off_user, off_item, csr_user, csr_item,
        max(n_user, n_item));

    // gather + mean
    dim3 gG((max(n_user, n_item) + 3) / 4, 2);
    gather2_kernel<<<gG, 256, 0, stream>>>(
        Wh_user, Wh_item, csr_user, csr_item, off_user, off_item,
        deg_user, deg_item, h_user, h_item, n_user, n_item);
}

// Round 5
// 392.233 us; speedup vs baseline: 2.7814x; 1.0017x over previous
//
#include <hip/hip_runtime.h>

#define D 64
#define NB 512            // dst buckets (bucket = dst >> 8); covers n < 131072
#define CHUNK 4096        // edges per bucket_fill/count block
#define EPT (CHUNK / 256) // 16 edges per thread
#define TILE 64           // rows per linear block

static __device__ __forceinline__ unsigned short f2bf(float x) {
    unsigned int u = __float_as_uint(x);
    unsigned int r = (u + 0x7FFFu + ((u >> 16) & 1u)) >> 16;   // RNE
    return (unsigned short)r;
}
static __device__ __forceinline__ float bf2f(unsigned short h) {
    return __uint_as_float((unsigned int)h << 16);
}

// ---------------- Linear: Whb = bf16(feat @ W^T + b), 64x64x64 tile GEMM ----------------
__global__ __launch_bounds__(256) void linear_gemm(
    const float* __restrict__ feat_u, const float* __restrict__ feat_i,
    const float* __restrict__ W_c, const float* __restrict__ b_c,
    const float* __restrict__ W_cb, const float* __restrict__ b_cb,
    unsigned short* __restrict__ Whb_u, unsigned short* __restrict__ Whb_i,
    int n_user, int n_item) {
    const float* feat; const float* W; const float* bia; unsigned short* out; int n;
    if (blockIdx.y == 0) { feat = feat_u; W = W_c;  bia = b_c;  out = Whb_u; n = n_user; }
    else                 { feat = feat_i; W = W_cb; bia = b_cb; out = Whb_i; n = n_item; }
    int row0 = blockIdx.x * TILE;
    if (row0 >= n) return;
    __shared__ float FT[D * 68];   // FT[k*68 + r] = feat[row0+r][k]
    __shared__ float WT[D * 68];   // WT[k*68 + c] = W[c][k]
    int t = threadIdx.x;
    int lr = t >> 4;               // 0..15
    int k4 = (t & 15) * 4;
    #pragma unroll
    for (int it = 0; it < 4; ++it) {
        int r = lr + it * 16;      // 0..63
        int grow = row0 + r; if (grow > n - 1) grow = n - 1;
        float4 f = *(const float4*)(feat + (size_t)grow * D + k4);
        FT[(k4 + 0) * 68 + r] = f.x;
        FT[(k4 + 1) * 68 + r] = f.y;
        FT[(k4 + 2) * 68 + r] = f.z;
        FT[(k4 + 3) * 68 + r] = f.w;
        float4 w = *(const float4*)(W + r * D + k4);   // W[col=r][k4..k4+3]
        WT[(k4 + 0) * 68 + r] = w.x;
        WT[(k4 + 1) * 68 + r] = w.y;
        WT[(k4 + 2) * 68 + r] = w.z;
        WT[(k4 + 3) * 68 + r] = w.w;
    }
    __syncthreads();
    int r0 = (t & 15) * 4;
    int c0 = (t >> 4) * 4;
    float4 bv = *(const float4*)(bia + c0);
    float acc[4][4];
    #pragma unroll
    for (int ri = 0; ri < 4; ++ri) {
        acc[ri][0] = bv.x; acc[ri][1] = bv.y; acc[ri][2] = bv.z; acc[ri][3] = bv.w;
    }
    #pragma unroll
    for (int k = 0; k < D; ++k) {
        float4 f = *(const float4*)(FT + k * 68 + r0);
        float4 w = *(const float4*)(WT + k * 68 + c0);
        acc[0][0] = fmaf(f.x, w.x, acc[0][0]); acc[0][1] = fmaf(f.x, w.y, acc[0][1]);
        acc[0][2] = fmaf(f.x, w.z, acc[0][2]); acc[0][3] = fmaf(f.x, w.w, acc[0][3]);
        acc[1][0] = fmaf(f.y, w.x, acc[1][0]); acc[1][1] = fmaf(f.y, w.y, acc[1][1]);
        acc[1][2] = fmaf(f.y, w.z, acc[1][2]); acc[1][3] = fmaf(f.y, w.w, acc[1][3]);
        acc[2][0] = fmaf(f.z, w.x, acc[2][0]); acc[2][1] = fmaf(f.z, w.y, acc[2][1]);
        acc[2][2] = fmaf(f.z, w.z, acc[2][2]); acc[2][3] = fmaf(f.z, w.w, acc[2][3]);
        acc[3][0] = fmaf(f.w, w.x, acc[3][0]); acc[3][1] = fmaf(f.w, w.y, acc[3][1]);
        acc[3][2] = fmaf(f.w, w.z, acc[3][2]); acc[3][3] = fmaf(f.w, w.w, acc[3][3]);
    }
    #pragma unroll
    for (int ri = 0; ri < 4; ++ri) {
        int row = row0 + r0 + ri;
        if (row < n) {
            ushort4 o;
            o.x = f2bf(acc[ri][0]); o.y = f2bf(acc[ri][1]);
            o.z = f2bf(acc[ri][2]); o.w = f2bf(acc[ri][3]);
            *(ushort4*)(out + (size_t)row * D + c0) = o;
        }
    }
}

// ---------------- Pass A: coarse bucket histogram ----------------
__global__ __launch_bounds__(256) void bucket_count(
    const int* __restrict__ dstA, const int* __restrict__ dstB,
    int* __restrict__ bcnt, int n_edges) {
    const int* dst = blockIdx.y ? dstB : dstA;
    int* bc = bcnt + blockIdx.y * NB;
    __shared__ int hist[NB];
    int t = threadIdx.x;
    for (int i = t; i < NB; i += 256) hist[i] = 0;
    __syncthreads();
    int base = blockIdx.x * CHUNK;
    #pragma unroll
    for (int j = 0; j < EPT; ++j) {
        int e = base + j * 256 + t;
        if (e < n_edges) atomicAdd(&hist[((unsigned)dst[e]) >> 8], 1);
    }
    __syncthreads();
    for (int i = t; i < NB; i += 256) if (hist[i]) atomicAdd(&bc[i], hist[i]);
}

// ---------------- tiny scan over NB bucket counts ----------------
__global__ __launch_bounds__(256) void bucket_scan(
    const int* __restrict__ bcnt, int* __restrict__ bbase, int* __restrict__ bcur) {
    int rel = blockIdx.y;
    const int* bc = bcnt + rel * NB;
    int* bb = bbase + rel * NB;
    int* bu = bcur + rel * NB;
    __shared__ int ps[256];
    int t = threadIdx.x;
    int a0 = bc[2 * t], a1 = bc[2 * t + 1];
    ps[t] = a0 + a1;
    __syncthreads();
    for (int o = 1; o < 256; o <<= 1) {
        int x = (t >= o) ? ps[t - o] : 0;
        __syncthreads();
        ps[t] += x;
        __syncthreads();
    }
    int ex = ps[t] - (a0 + a1);
    bb[2 * t] = ex;          bu[2 * t] = ex;
    bb[2 * t + 1] = ex + a0; bu[2 * t + 1] = ex + a0;
}

// ---------------- Pass B: bucket-partition edges (LDS reorder, run writes) ----------------
__global__ __launch_bounds__(256) void bucket_fill(
    const int* __restrict__ srcA, const int* __restrict__ dstA,
    const int* __restrict__ srcB, const int* __restrict__ dstB,
    int* __restrict__ bcur,
    unsigned int* __restrict__ ebufA, unsigned int* __restrict__ ebufB,
    int n_edges) {
    int rel = blockIdx.y;
    const int* src = rel ? srcB : srcA;
    const int* dst = rel ? dstB : dstA;
    int* bu = bcur + rel * NB;
    unsigned int* ebuf = rel ? ebufB : ebufA;
    __shared__ int hist[NB], lofs[NB], lcur[NB], runb[NB];
    __shared__ unsigned int stage[CHUNK];
    __shared__ unsigned short sbkt[CHUNK];
    __shared__ int ps[256];
    int t = threadIdx.x;
    for (int i = t; i < NB; i += 256) hist[i] = 0;
    __syncthreads();
    int base = blockIdx.x * CHUNK;
    int m = n_edges - base; if (m > CHUNK) m = CHUNK;
    unsigned int packed[EPT];
    int bk[EPT];
    #pragma unroll
    for (int j = 0; j < EPT; ++j) {
        int e = base + j * 256 + t;
        if (e < n_edges) {
            int d = dst[e];
            int s = src[e];
            bk[j] = ((unsigned)d) >> 8;
            packed[j] = (unsigned int)s | (((unsigned int)d & 255u) << 24);
            atomicAdd(&hist[bk[j]], 1);
        } else bk[j] = -1;
    }
    __syncthreads();
    int a0 = hist[2 * t], a1 = hist[2 * t + 1];
    ps[t] = a0 + a1;
    __syncthreads();
    for (int o = 1; o < 256; o <<= 1) {
        int x = (t >= o) ? ps[t - o] : 0;
        __syncthreads();
        ps[t] += x;
        __syncthreads();
    }
    int ex = ps[t] - (a0 + a1);
    lofs[2 * t] = ex;          lcur[2 * t] = ex;
    lofs[2 * t + 1] = ex + a0; lcur[2 * t + 1] = ex + a0;
    __syncthreads();
    for (int b = t; b < NB; b += 256) {
        int c = hist[b];
        runb[b] = c ? atomicAdd(&bu[b], c) : 0;
    }
    #pragma unroll
    for (int j = 0; j < EPT; ++j) {
        if (bk[j] >= 0) {
            int p = atomicAdd(&lcur[bk[j]], 1);
            stage[p] = packed[j];
            sbkt[p] = (unsigned short)bk[j];
        }
    }
    __syncthreads();
    for (int i = t; i < m; i += 256) {
        int b = sbkt[i];
        ebuf[runb[b] + (i - lofs[b])] = stage[i];
    }
}

// ---------------- Pass C: per-bucket node degrees, offsets, csr ----------------
__global__ __launch_bounds__(256) void bucket_csr(
    const unsigned int* __restrict__ ebufA, const unsigned int* __restrict__ ebufB,
    const int* __restrict__ bcnt, const int* __restrict__ bbase,
    int* __restrict__ degA, int* __restrict__ degB,
    int* __restrict__ offA, int* __restrict__ offB,
    int* __restrict__ csrA, int* __restrict__ csrB, int n) {
    int rel = blockIdx.y;
    const unsigned int* ebuf = rel ? ebufB : ebufA;
    int* deg = rel ? degB : degA;
    int* off = rel ? offB : offA;
    int* csr = rel ? csrB : csrA;
    int b = blockIdx.x;
    int cnt = bcnt[rel * NB + b];
    int eb  = bbase[rel * NB + b];
    __shared__ int ndeg[256], nofs[256], ncur[256];
    int t = threadIdx.x;
    ndeg[t] = 0;
    __syncthreads();
    for (int i = t; i < cnt; i += 256)
        atomicAdd(&ndeg[ebuf[eb + i] >> 24], 1);
    __syncthreads();
    int own = ndeg[t];
    nofs[t] = own;
    __syncthreads();
    for (int o = 1; o < 256; o <<= 1) {
        int x = (t >= o) ? nofs[t - o] : 0;
        __syncthreads();
        nofs[t] += x;
        __syncthreads();
    }
    int ex = nofs[t] - own;
    int node = b * 256 + t;
    if (node < n) { deg[node] = own; off[node] = eb + ex; }
    ncur[t] = ex;
    __syncthreads();
    for (int i = t; i < cnt; i += 256) {
        unsigned int v = ebuf[eb + i];
        int ln = v >> 24;
        int p = atomicAdd(&ncur[ln], 1);
        csr[eb + p] = (int)(v & 0xFFFFFFu);
    }
}

// ---------------- gather + mean: one wave per dst node, bf16 Wh ----------------
__global__ __launch_bounds__(256) void gather2_kernel(
    const unsigned short* __restrict__ Whb_u, const unsigned short* __restrict__ Whb_i,
    const int* __restrict__ csr_u, const int* __restrict__ csr_i,
    const int* __restrict__ off_u, const int* __restrict__ off_i,
    const int* __restrict__ deg_u, const int* __restrict__ deg_i,
    float* __restrict__ h_user, float* __restrict__ h_item,
    int n_user, int n_item) {
    const unsigned short* Wh; const int* csr; const int* off; const int* deg;
    float* out; int n;
    if (blockIdx.y == 0) { Wh = Whb_i; csr = csr_u; off = off_u; deg = deg_u; out = h_user; n = n_user; }
    else                 { Wh = Whb_u; csr = csr_i; off = off_i; deg = deg_i; out = h_item; n = n_item; }
    int t = threadIdx.x;
    int node = blockIdx.x * 4 + (t >> 6);
    int lane = t & 63;
    if (node >= n) return;
    int start = off[node];
    int dg = deg[node];
    float acc0 = 0.f, acc1 = 0.f;
    for (int base = 0; base < dg; base += 64) {
        int m = min(64, dg - base);
        int sidx = (lane < m) ? csr[start + base + lane] : 0;
        int j = 0;
        for (; j + 1 < m; j += 2) {
            int s0 = __shfl(sidx, j, 64);
            int s1 = __shfl(sidx, j + 1, 64);
            acc0 += bf2f(Wh[(size_t)s0 * D + lane]);
            acc1 += bf2f(Wh[(size_t)s1 * D + lane]);
        }
        if (j < m) {
            int s0 = __shfl(sidx, j, 64);
            acc0 += bf2f(Wh[(size_t)s0 * D + lane]);
        }
    }
    out[(size_t)node * D + lane] = (acc0 + acc1) / fmaxf((float)dg, 1.0f);
}

extern "C" void kernel_launch(void* const* d_in, const int* in_sizes, int n_in,
                              void* d_out, int out_size, void* d_ws, size_t ws_size,
                              hipStream_t stream) {
    const float* feat_user      = (const float*)d_in[0];
    const float* feat_item      = (const float*)d_in[1];
    const int*   src_clicks     = (const int*)d_in[2];   // user ids
    const int*   dst_clicks     = (const int*)d_in[3];   // item ids
    const int*   src_clicked_by = (const int*)d_in[4];   // item ids
    const int*   dst_clicked_by = (const int*)d_in[5];   // user ids
    const float* W_clicks       = (const float*)d_in[6];
    const float* b_clicks       = (const float*)d_in[7];
    const float* W_clicked_by   = (const float*)d_in[8];
    const float* b_clicked_by   = (const float*)d_in[9];

    const int n_user  = in_sizes[0] / D;
    const int n_item  = in_sizes[1] / D;
    const int n_edges = in_sizes[2];

    float* out = (float*)d_out;
    float* h_user = out;
    float* h_item = out + (size_t)n_user * D;

    unsigned short* Whb_user = (unsigned short*)d_ws;             // [n_user*64] bf16
    unsigned short* Whb_item = Whb_user + (size_t)n_user * D;     // [n_item*64] bf16
    int* ip        = (int*)(Whb_item + (size_t)n_item * D);
    int* deg_user  = ip;                      ip += n_user;
    int* deg_item  = ip;                      ip += n_item;
    int* off_user  = ip;                      ip += n_user;
    int* off_item  = ip;                      ip += n_item;
    int* csr_user  = ip;                      ip += n_edges;
    int* csr_item  = ip;                      ip += n_edges;
    unsigned int* ebuf_user = (unsigned int*)ip;  ip += n_edges;
    unsigned int* ebuf_item = (unsigned int*)ip;  ip += n_edges;
    int* bcnt  = ip;                          ip += 2 * NB;
    int* bbase = ip;                          ip += 2 * NB;
    int* bcur  = ip;

    hipMemsetAsync(bcnt, 0, 2 * NB * sizeof(int), stream);

    int ntile = (max(n_user, n_item) + TILE - 1) / TILE;
    linear_gemm<<<dim3(ntile, 2), 256, 0, stream>>>(
        feat_user, feat_item, W_clicks, b_clicks, W_clicked_by, b_clicked_by,
        Whb_user, Whb_item, n_user, n_item);

    int eb = (n_edges + CHUNK - 1) / CHUNK;
    bucket_count<<<dim3(eb, 2), 256, 0, stream>>>(dst_clicked_by, dst_clicks, bcnt, n_edges);
    bucket_scan<<<dim3(1, 2), 256, 0, stream>>>(bcnt, bbase, bcur);
    bucket_fill<<<dim3(eb, 2), 256, 0, stream>>>(
        src_clicked_by, dst_clicked_by, src_clicks, dst_clicks,
        bcur, ebuf_user, ebuf_item, n_edges);
    int nbk = (max(n_user, n_item) + 255) >> 8;
    bucket_csr<<<dim3(nbk, 2), 256, 0, stream>>>(
        ebuf_user, ebuf_item, bcnt, bbase,
        deg_user, deg_item, off_user, off_item, csr_user, csr_item,
        max(n_user, n_item));

    dim3 gG((max(n_user, n_item) + 3) / 4, 2);
    gather2_kernel<<<gG, 256, 0, stream>>>(
        Whb_user, Whb_item, csr_user, csr_item, off_user, off_item,
        deg_user, deg_item, h_user, h_item, n_user, n_item);
}

// Round 6
// 279.618 us; speedup vs baseline: 3.9016x; 1.4027x over previous
//
#include <hip/hip_runtime.h>

#define D 64
#define NB 512            // dst buckets (bucket = dst >> 8); covers n < 131072
#define CHUNK 4096        // edges per bucket_fill/count block
#define EPT (CHUNK / 256) // 16 edges per thread
#define TILE 64           // rows per linear block

static __device__ __forceinline__ unsigned short f2bf(float x) {
    unsigned int u = __float_as_uint(x);
    unsigned int r = (u + 0x7FFFu + ((u >> 16) & 1u)) >> 16;   // RNE
    return (unsigned short)r;
}
static __device__ __forceinline__ float bf2f(unsigned short h) {
    return __uint_as_float((unsigned int)h << 16);
}

// ---------------- Linear: Whb = bf16(feat @ W^T + b) ----------------
// FT row-major (f-reads are wave broadcasts: free); WT transposed stride 68
// (b128 reads over cols). c0 from low lane bits -> coalesced bf16 row stores.
__global__ __launch_bounds__(256) void linear_gemm(
    const float* __restrict__ feat_u, const float* __restrict__ feat_i,
    const float* __restrict__ W_c, const float* __restrict__ b_c,
    const float* __restrict__ W_cb, const float* __restrict__ b_cb,
    unsigned short* __restrict__ Whb_u, unsigned short* __restrict__ Whb_i,
    int n_user, int n_item) {
    const float* feat; const float* W; const float* bia; unsigned short* out; int n;
    if (blockIdx.y == 0) { feat = feat_u; W = W_c;  bia = b_c;  out = Whb_u; n = n_user; }
    else                 { feat = feat_i; W = W_cb; bia = b_cb; out = Whb_i; n = n_item; }
    int row0 = blockIdx.x * TILE;
    if (row0 >= n) return;
    __shared__ float FT[TILE * D];   // row-major: FT[r*64 + k]
    __shared__ float WT[D * 68];     // transposed: WT[k*68 + c] = W[c][k]
    int t = threadIdx.x;
    int lr = t >> 4;                 // 0..15
    int k4 = (t & 15) * 4;
    #pragma unroll
    for (int it = 0; it < 4; ++it) {
        int r = lr + it * 16;        // 0..63
        int grow = row0 + r; if (grow > n - 1) grow = n - 1;
        float4 f = *(const float4*)(feat + (size_t)grow * D + k4);
        *(float4*)(FT + r * D + k4) = f;            // conflict-free b128 store
        float4 w = *(const float4*)(W + r * D + k4);  // W[col=r][k4..k4+3]
        WT[(k4 + 0) * 68 + r] = w.x;                // one-time transpose
        WT[(k4 + 1) * 68 + r] = w.y;
        WT[(k4 + 2) * 68 + r] = w.z;
        WT[(k4 + 3) * 68 + r] = w.w;
    }
    __syncthreads();
    int c0 = (t & 15) * 4;           // cols on low bits -> coalesced stores
    int r0 = (t >> 4) * 4;           // rows on high bits
    float4 bv = *(const float4*)(bia + c0);
    float acc[4][4];                 // [ri][ci]
    #pragma unroll
    for (int ri = 0; ri < 4; ++ri) {
        acc[ri][0] = bv.x; acc[ri][1] = bv.y; acc[ri][2] = bv.z; acc[ri][3] = bv.w;
    }
    #pragma unroll 4
    for (int k = 0; k < D; ++k) {
        float4 w = *(const float4*)(WT + k * 68 + c0);
        float f0 = FT[(r0 + 0) * D + k];
        float f1 = FT[(r0 + 1) * D + k];
        float f2 = FT[(r0 + 2) * D + k];
        float f3 = FT[(r0 + 3) * D + k];
        acc[0][0] = fmaf(f0, w.x, acc[0][0]); acc[0][1] = fmaf(f0, w.y, acc[0][1]);
        acc[0][2] = fmaf(f0, w.z, acc[0][2]); acc[0][3] = fmaf(f0, w.w, acc[0][3]);
        acc[1][0] = fmaf(f1, w.x, acc[1][0]); acc[1][1] = fmaf(f1, w.y, acc[1][1]);
        acc[1][2] = fmaf(f1, w.z, acc[1][2]); acc[1][3] = fmaf(f1, w.w, acc[1][3]);
        acc[2][0] = fmaf(f2, w.x, acc[2][0]); acc[2][1] = fmaf(f2, w.y, acc[2][1]);
        acc[2][2] = fmaf(f2, w.z, acc[2][2]); acc[2][3] = fmaf(f2, w.w, acc[2][3]);
        acc[3][0] = fmaf(f3, w.x, acc[3][0]); acc[3][1] = fmaf(f3, w.y, acc[3][1]);
        acc[3][2] = fmaf(f3, w.z, acc[3][2]); acc[3][3] = fmaf(f3, w.w, acc[3][3]);
    }
    #pragma unroll
    for (int ri = 0; ri < 4; ++ri) {
        int row = row0 + r0 + ri;
        if (row < n) {
            ushort4 o;
            o.x = f2bf(acc[ri][0]); o.y = f2bf(acc[ri][1]);
            o.z = f2bf(acc[ri][2]); o.w = f2bf(acc[ri][3]);
            *(ushort4*)(out + (size_t)row * D + c0) = o;   // 16 lanes = one 128B row
        }
    }
}

// ---------------- Pass A: coarse bucket histogram ----------------
__global__ __launch_bounds__(256) void bucket_count(
    const int* __restrict__ dstA, const int* __restrict__ dstB,
    int* __restrict__ bcnt, int n_edges) {
    const int* dst = blockIdx.y ? dstB : dstA;
    int* bc = bcnt + blockIdx.y * NB;
    __shared__ int hist[NB];
    int t = threadIdx.x;
    for (int i = t; i < NB; i += 256) hist[i] = 0;
    __syncthreads();
    int base = blockIdx.x * CHUNK;
    #pragma unroll
    for (int j = 0; j < EPT; ++j) {
        int e = base + j * 256 + t;
        if (e < n_edges) atomicAdd(&hist[((unsigned)dst[e]) >> 8], 1);
    }
    __syncthreads();
    for (int i = t; i < NB; i += 256) if (hist[i]) atomicAdd(&bc[i], hist[i]);
}

// ---------------- tiny scan over NB bucket counts ----------------
__global__ __launch_bounds__(256) void bucket_scan(
    const int* __restrict__ bcnt, int* __restrict__ bbase, int* __restrict__ bcur) {
    int rel = blockIdx.y;
    const int* bc = bcnt + rel * NB;
    int* bb = bbase + rel * NB;
    int* bu = bcur + rel * NB;
    __shared__ int ps[256];
    int t = threadIdx.x;
    int a0 = bc[2 * t], a1 = bc[2 * t + 1];
    ps[t] = a0 + a1;
    __syncthreads();
    for (int o = 1; o < 256; o <<= 1) {
        int x = (t >= o) ? ps[t - o] : 0;
        __syncthreads();
        ps[t] += x;
        __syncthreads();
    }
    int ex = ps[t] - (a0 + a1);
    bb[2 * t] = ex;          bu[2 * t] = ex;
    bb[2 * t + 1] = ex + a0; bu[2 * t + 1] = ex + a0;
}

// ---------------- Pass B: bucket-partition edges (LDS reorder, run writes) ----------------
__global__ __launch_bounds__(256) void bucket_fill(
    const int* __restrict__ srcA, const int* __restrict__ dstA,
    const int* __restrict__ srcB, const int* __restrict__ dstB,
    int* __restrict__ bcur,
    unsigned int* __restrict__ ebufA, unsigned int* __restrict__ ebufB,
    int n_edges) {
    int rel = blockIdx.y;
    const int* src = rel ? srcB : srcA;
    const int* dst = rel ? dstB : dstA;
    int* bu = bcur + rel * NB;
    unsigned int* ebuf = rel ? ebufB : ebufA;
    __shared__ int hist[NB], lofs[NB], lcur[NB], runb[NB];
    __shared__ unsigned int stage[CHUNK];
    __shared__ unsigned short sbkt[CHUNK];
    __shared__ int ps[256];
    int t = threadIdx.x;
    for (int i = t; i < NB; i += 256) hist[i] = 0;
    __syncthreads();
    int base = blockIdx.x * CHUNK;
    int m = n_edges - base; if (m > CHUNK) m = CHUNK;
    unsigned int packed[EPT];
    int bk[EPT];
    #pragma unroll
    for (int j = 0; j < EPT; ++j) {
        int e = base + j * 256 + t;
        if (e < n_edges) {
            int d = dst[e];
            int s = src[e];
            bk[j] = ((unsigned)d) >> 8;
            packed[j] = (unsigned int)s | (((unsigned int)d & 255u) << 24);
            atomicAdd(&hist[bk[j]], 1);
        } else bk[j] = -1;
    }
    __syncthreads();
    int a0 = hist[2 * t], a1 = hist[2 * t + 1];
    ps[t] = a0 + a1;
    __syncthreads();
    for (int o = 1; o < 256; o <<= 1) {
        int x = (t >= o) ? ps[t - o] : 0;
        __syncthreads();
        ps[t] += x;
        __syncthreads();
    }
    int ex = ps[t] - (a0 + a1);
    lofs[2 * t] = ex;          lcur[2 * t] = ex;
    lofs[2 * t + 1] = ex + a0; lcur[2 * t + 1] = ex + a0;
    __syncthreads();
    for (int b = t; b < NB; b += 256) {
        int c = hist[b];
        runb[b] = c ? atomicAdd(&bu[b], c) : 0;
    }
    #pragma unroll
    for (int j = 0; j < EPT; ++j) {
        if (bk[j] >= 0) {
            int p = atomicAdd(&lcur[bk[j]], 1);
            stage[p] = packed[j];
            sbkt[p] = (unsigned short)bk[j];
        }
    }
    __syncthreads();
    for (int i = t; i < m; i += 256) {
        int b = sbkt[i];
        ebuf[runb[b] + (i - lofs[b])] = stage[i];
    }
}

// ---------------- Pass C: per-bucket node degrees, offsets, csr ----------------
__global__ __launch_bounds__(256) void bucket_csr(
    const unsigned int* __restrict__ ebufA, const unsigned int* __restrict__ ebufB,
    const int* __restrict__ bcnt, const int* __restrict__ bbase,
    int* __restrict__ degA, int* __restrict__ degB,
    int* __restrict__ offA, int* __restrict__ offB,
    int* __restrict__ csrA, int* __restrict__ csrB, int n) {
    int rel = blockIdx.y;
    const unsigned int* ebuf = rel ? ebufB : ebufA;
    int* deg = rel ? degB : degA;
    int* off = rel ? offB : offA;
    int* csr = rel ? csrB : csrA;
    int b = blockIdx.x;
    int cnt = bcnt[rel * NB + b];
    int eb  = bbase[rel * NB + b];
    __shared__ int ndeg[256], nofs[256], ncur[256];
    int t = threadIdx.x;
    ndeg[t] = 0;
    __syncthreads();
    for (int i = t; i < cnt; i += 256)
        atomicAdd(&ndeg[ebuf[eb + i] >> 24], 1);
    __syncthreads();
    int own = ndeg[t];
    nofs[t] = own;
    __syncthreads();
    for (int o = 1; o < 256; o <<= 1) {
        int x = (t >= o) ? nofs[t - o] : 0;
        __syncthreads();
        nofs[t] += x;
        __syncthreads();
    }
    int ex = nofs[t] - own;
    int node = b * 256 + t;
    if (node < n) { deg[node] = own; off[node] = eb + ex; }
    ncur[t] = ex;
    __syncthreads();
    for (int i = t; i < cnt; i += 256) {
        unsigned int v = ebuf[eb + i];
        int ln = v >> 24;
        int p = atomicAdd(&ncur[ln], 1);
        csr[eb + p] = (int)(v & 0xFFFFFFu);
    }
}

// ---------------- gather + mean: one wave per dst node, bf16 Wh ----------------
__global__ __launch_bounds__(256) void gather2_kernel(
    const unsigned short* __restrict__ Whb_u, const unsigned short* __restrict__ Whb_i,
    const int* __restrict__ csr_u, const int* __restrict__ csr_i,
    const int* __restrict__ off_u, const int* __restrict__ off_i,
    const int* __restrict__ deg_u, const int* __restrict__ deg_i,
    float* __restrict__ h_user, float* __restrict__ h_item,
    int n_user, int n_item) {
    const unsigned short* Wh; const int* csr; const int* off; const int* deg;
    float* out; int n;
    if (blockIdx.y == 0) { Wh = Whb_i; csr = csr_u; off = off_u; deg = deg_u; out = h_user; n = n_user; }
    else                 { Wh = Whb_u; csr = csr_i; off = off_i; deg = deg_i; out = h_item; n = n_item; }
    int t = threadIdx.x;
    int node = blockIdx.x * 4 + (t >> 6);
    int lane = t & 63;
    if (node >= n) return;
    int start = off[node];
    int dg = deg[node];
    float acc0 = 0.f, acc1 = 0.f;
    for (int base = 0; base < dg; base += 64) {
        int m = min(64, dg - base);
        int sidx = (lane < m) ? csr[start + base + lane] : 0;
        int j = 0;
        for (; j + 1 < m; j += 2) {
            int s0 = __shfl(sidx, j, 64);
            int s1 = __shfl(sidx, j + 1, 64);
            acc0 += bf2f(Wh[(size_t)s0 * D + lane]);
            acc1 += bf2f(Wh[(size_t)s1 * D + lane]);
        }
        if (j < m) {
            int s0 = __shfl(sidx, j, 64);
            acc0 += bf2f(Wh[(size_t)s0 * D + lane]);
        }
    }
    out[(size_t)node * D + lane] = (acc0 + acc1) / fmaxf((float)dg, 1.0f);
}

extern "C" void kernel_launch(void* const* d_in, const int* in_sizes, int n_in,
                              void* d_out, int out_size, void* d_ws, size_t ws_size,
                              hipStream_t stream) {
    const float* feat_user      = (const float*)d_in[0];
    const float* feat_item      = (const float*)d_in[1];
    const int*   src_clicks     = (const int*)d_in[2];   // user ids
    const int*   dst_clicks     = (const int*)d_in[3];   // item ids
    const int*   src_clicked_by = (const int*)d_in[4];   // item ids
    const int*   dst_clicked_by = (const int*)d_in[5];   // user ids
    const float* W_clicks       = (const float*)d_in[6];
    const float* b_clicks       = (const float*)d_in[7];
    const float* W_clicked_by   = (const float*)d_in[8];
    const float* b_clicked_by   = (const float*)d_in[9];

    const int n_user  = in_sizes[0] / D;
    const int n_item  = in_sizes[1] / D;
    const int n_edges = in_sizes[2];

    float* out = (float*)d_out;
    float* h_user = out;
    float* h_item = out + (size_t)n_user * D;

    unsigned short* Whb_user = (unsigned short*)d_ws;             // [n_user*64] bf16
    unsigned short* Whb_item = Whb_user + (size_t)n_user * D;     // [n_item*64] bf16
    int* ip        = (int*)(Whb_item + (size_t)n_item * D);
    int* deg_user  = ip;                      ip += n_user;
    int* deg_item  = ip;                      ip += n_item;
    int* off_user  = ip;                      ip += n_user;
    int* off_item  = ip;                      ip += n_item;
    int* csr_user  = ip;                      ip += n_edges;
    int* csr_item  = ip;                      ip += n_edges;
    unsigned int* ebuf_user = (unsigned int*)ip;  ip += n_edges;
    unsigned int* ebuf_item = (unsigned int*)ip;  ip += n_edges;
    int* bcnt  = ip;                          ip += 2 * NB;
    int* bbase = ip;                          ip += 2 * NB;
    int* bcur  = ip;

    hipMemsetAsync(bcnt, 0, 2 * NB * sizeof(int), stream);

    int ntile = (max(n_user, n_item) + TILE - 1) / TILE;
    linear_gemm<<<dim3(ntile, 2), 256, 0, stream>>>(
        feat_user, feat_item, W_clicks, b_clicks, W_clicked_by, b_clicked_by,
        Whb_user, Whb_item, n_user, n_item);

    int eb = (n_edges + CHUNK - 1) / CHUNK;
    bucket_count<<<dim3(eb, 2), 256, 0, stream>>>(dst_clicked_by, dst_clicks, bcnt, n_edges);
    bucket_scan<<<dim3(1, 2), 256, 0, stream>>>(bcnt, bbase, bcur);
    bucket_fill<<<dim3(eb, 2), 256, 0, stream>>>(
        src_clicked_by, dst_clicked_by, src_clicks, dst_clicks,
        bcur, ebuf_user, ebuf_item, n_edges);
    int nbk = (max(n_user, n_item) + 255) >> 8;
    bucket_csr<<<dim3(nbk, 2), 256, 0, stream>>>(
        ebuf_user, ebuf_item, bcnt, bbase,
        deg_user, deg_item, off_user, off_item, csr_user, csr_item,
        max(n_user, n_item));

    dim3 gG((max(n_user, n_item) + 3) / 4, 2);
    gather2_kernel<<<gG, 256, 0, stream>>>(
        Whb_user, Whb_item, csr_user, csr_item, off_user, off_item,
        deg_user, deg_item, h_user, h_item, n_user, n_item);
}